// Round 2
// baseline (325.287 us; speedup 1.0000x reference)
//
#include <hip/hip_runtime.h>
#include <hip/hip_bf16.h>
#include <math.h>

// Problem constants
#define TDIM 4096
#define CDIM 256
#define BDIM 8
#define NTOK (BDIM * TDIM)   // 32768 rows
#define HIDDIM 1024
#define NCHUNK 64
#define CHLEN 64             // 4096 / 64

typedef float f32x4 __attribute__((ext_vector_type(4)));
typedef __bf16 bf16x8 __attribute__((ext_vector_type(8)));
typedef __bf16 bf16x4 __attribute__((ext_vector_type(4)));

// async global->LDS, 16 B/lane, lands at wave-uniform base + lane*16
#define GLDS16(gp, lp) __builtin_amdgcn_global_load_lds( \
    (const __attribute__((address_space(1))) void*)(gp), \
    (__attribute__((address_space(3))) void*)(lp), 16, 0, 0)

// ---------------------------------------------------------------------------
// Weight pack: fp32 [K,N] -> bf16 transposed [N,K].
// ---------------------------------------------------------------------------
__global__ __launch_bounds__(256) void pack_weights(
    const float* __restrict__ Wk, const float* __restrict__ Wv,
    const float* __restrict__ Wr, const float* __restrict__ Wo,
    const float* __restrict__ Wkf, const float* __restrict__ Wvf,
    const float* __restrict__ Wrf,
    __bf16* __restrict__ WkvrT, __bf16* __restrict__ WoT,
    __bf16* __restrict__ WkfT, __bf16* __restrict__ WvfT,
    __bf16* __restrict__ WrfT) {
  long long j = (long long)blockIdx.x * 256 + threadIdx.x;
  if (j < 196608) {  // WkvrT: [768][256]
    int n = (int)(j >> 8), k = (int)(j & 255);
    const float* src = (n < 256) ? Wk : (n < 512 ? Wv : Wr);
    WkvrT[j] = (__bf16)src[k * 256 + (n & 255)];
    return;
  }
  j -= 196608;
  if (j < 65536) { int n = (int)(j >> 8), k = (int)(j & 255);
    WoT[j] = (__bf16)Wo[k * 256 + n]; return; }
  j -= 65536;
  if (j < 262144) { int n = (int)(j >> 8), k = (int)(j & 255);   // WkfT [1024][256]
    WkfT[j] = (__bf16)Wkf[(long long)k * 1024 + n]; return; }
  j -= 262144;
  if (j < 262144) { int n = (int)(j >> 10), k = (int)(j & 1023); // WvfT [256][1024]
    WvfT[j] = (__bf16)Wvf[(long long)k * 256 + n]; return; }
  j -= 262144;
  if (j < 65536) { int n = (int)(j >> 8), k = (int)(j & 255);
    WrfT[j] = (__bf16)Wrf[k * 256 + n]; return; }
}

// ---------------------------------------------------------------------------
// LayerNorm over C=256, one block per row, bf16 output.
// ---------------------------------------------------------------------------
__global__ __launch_bounds__(256) void ln_kernel(
    const float* __restrict__ x, const float* __restrict__ gamma,
    const float* __restrict__ beta, __bf16* __restrict__ h) {
  __shared__ float red[8];
  const long long row = blockIdx.x;
  const int tid = threadIdx.x;
  float v = x[row * CDIM + tid];
  float s = v, s2 = v * v;
  #pragma unroll
  for (int o = 1; o < 64; o <<= 1) { s += __shfl_xor(s, o); s2 += __shfl_xor(s2, o); }
  const int wave = tid >> 6, lane = tid & 63;
  if (lane == 0) { red[wave] = s; red[4 + wave] = s2; }
  __syncthreads();
  s = red[0] + red[1] + red[2] + red[3];
  s2 = red[4] + red[5] + red[6] + red[7];
  const float mean = s * (1.0f / CDIM);
  const float var = s2 * (1.0f / CDIM) - mean * mean;
  const float rstd = rsqrtf(var + 1e-5f);
  h[row * CDIM + tid] = (__bf16)((v - mean) * rstd * gamma[tid] + beta[tid]);
}

// ---------------------------------------------------------------------------
// bf16 MFMA GEMM: C[M,N] = A[M,K] * Bt[N,K]^T, global_load_lds staging.
// 128x128 tile, 4 waves x (64x64). Accumulator computed TRANSPOSED
// (mfma(fb,fa)): lane holds 4 consecutive COLUMNS -> float4/short4 epilogue.
// Epilogues: 0 bf16=acc | 1 f32=src+acc | 2 bf16=relu(acc)^2
//            3 bf16=sigmoid(acc) | 4 f32=src+gate*acc
// ---------------------------------------------------------------------------
#define BM 128
#define BN 128
#define BK 32

template <int EPI>
__global__ __launch_bounds__(256) void gemm_kernel(
    const __bf16* __restrict__ A, const __bf16* __restrict__ Bt,
    int M, int N, int K,
    float* __restrict__ outF, __bf16* __restrict__ outH,
    const float* __restrict__ src, const __bf16* __restrict__ gate) {
  __shared__ __bf16 sA[BM * BK];   // unpadded row-major [row][k], 64 B/row
  __shared__ __bf16 sB[BN * BK];
  const int tid = threadIdx.x;
  const int wave = tid >> 6, lane = tid & 63;
  const int quad = lane >> 4, mrow = lane & 15;
  const long long bm = (long long)blockIdx.x * BM;
  const long long bn = (long long)blockIdx.y * BN;
  const int wm = (wave & 1) * 64, wn = (wave >> 1) * 64;

  // staging: wave w covers rows [w*32, w*32+32) of both tiles, 2 calls each
  const int lrow = lane >> 2;          // 0..15
  const int lk = (lane & 3) * 8;       // elem offset 0,8,16,24
  const int ar0 = wave * 32;

  f32x4 acc[4][4] = {};   // acc[rt][nt] = (A-tile rt x B-tile nt), TRANSPOSED

  #pragma unroll 1
  for (int k0 = 0; k0 < K; k0 += BK) {
    const __bf16* gA0 = A + (bm + ar0 + lrow) * (long long)K + k0 + lk;
    const __bf16* gB0 = Bt + (bn + ar0 + lrow) * (long long)K + k0 + lk;
    GLDS16(gA0, &sA[ar0 * BK]);
    GLDS16(gA0 + 16LL * K, &sA[(ar0 + 16) * BK]);
    GLDS16(gB0, &sB[ar0 * BK]);
    GLDS16(gB0 + 16LL * K, &sB[(ar0 + 16) * BK]);
    __syncthreads();

    bf16x8 fa[4], fb[4];
    #pragma unroll
    for (int rt = 0; rt < 4; rt++)
      fa[rt] = *(const bf16x8*)&sA[(wm + rt * 16 + mrow) * BK + quad * 8];
    #pragma unroll
    for (int nt = 0; nt < 4; nt++)
      fb[nt] = *(const bf16x8*)&sB[(wn + nt * 16 + mrow) * BK + quad * 8];
    #pragma unroll
    for (int rt = 0; rt < 4; rt++)
      #pragma unroll
      for (int nt = 0; nt < 4; nt++)
        acc[rt][nt] = __builtin_amdgcn_mfma_f32_16x16x32_bf16(fb[nt], fa[rt], acc[rt][nt], 0, 0, 0);
    __syncthreads();
  }

  // Transposed C/D layout: lane (quad,mrow) reg r -> row = m-tile + mrow,
  // col = n-tile + quad*4 + r. 4 consecutive cols per lane.
  #pragma unroll
  for (int rt = 0; rt < 4; rt++) {
    #pragma unroll
    for (int nt = 0; nt < 4; nt++) {
      const long long row = bm + wm + rt * 16 + mrow;
      const long long colb = bn + wn + nt * 16 + quad * 4;
      const long long idx = row * N + colb;
      const f32x4 a = acc[rt][nt];
      if (EPI == 0) {
        bf16x4 o; o[0] = (__bf16)a[0]; o[1] = (__bf16)a[1];
        o[2] = (__bf16)a[2]; o[3] = (__bf16)a[3];
        *(bf16x4*)&outH[idx] = o;
      } else if (EPI == 1) {
        *(f32x4*)&outF[idx] = *(const f32x4*)&src[idx] + a;
      } else if (EPI == 2) {
        bf16x4 o;
        #pragma unroll
        for (int r = 0; r < 4; r++) { float t = a[r] > 0.0f ? a[r] : 0.0f; o[r] = (__bf16)(t * t); }
        *(bf16x4*)&outH[idx] = o;
      } else if (EPI == 3) {
        bf16x4 o;
        #pragma unroll
        for (int r = 0; r < 4; r++) o[r] = (__bf16)(1.0f / (1.0f + __expf(-a[r])));
        *(bf16x4*)&outH[idx] = o;
      } else {
        const f32x4 s4 = *(const f32x4*)&src[idx];
        const bf16x4 g4 = *(const bf16x4*)&gate[idx];
        f32x4 o;
        #pragma unroll
        for (int r = 0; r < 4; r++) o[r] = s4[r] + (float)g4[r] * a[r];
        *(f32x4*)&outF[idx] = o;
      }
    }
  }
}

// ---------------------------------------------------------------------------
// WKV chunked scan (direct fp32 recurrence; exponents bounded: |w*T|<=5,
// |k|~O(2), u~0).  S' = e^w S + e^k v ; y = (S + e^{u+k} v)/(Z + e^{u+k})
// ---------------------------------------------------------------------------
__global__ __launch_bounds__(256) void wkv_phase1(
    const __bf16* __restrict__ kvr, const float* __restrict__ decay,
    float* __restrict__ Sloc, float* __restrict__ Zloc) {
  const int c = threadIdx.x;
  const int chunk = blockIdx.x & (NCHUNK - 1);
  const int b = blockIdx.x >> 6;
  const float w = decay[c] * (1.0f / TDIM);
  const float ew = __expf(w);
  float S = 0.0f, Z = 0.0f;
  long long base = ((long long)b * TDIM + (long long)chunk * CHLEN) * 768 + c;
  for (int t = 0; t < CHLEN; t++) {
    float kt = (float)kvr[base + (long long)t * 768];
    float vt = (float)kvr[base + (long long)t * 768 + 256];
    float ek = __expf(kt);
    S = ew * S + ek * vt;
    Z = ew * Z + ek;
  }
  long long o = ((long long)b * NCHUNK + chunk) * CDIM + c;
  Sloc[o] = S;
  Zloc[o] = Z;
}

__global__ __launch_bounds__(256) void wkv_phase2(
    const float* __restrict__ Sloc, const float* __restrict__ Zloc,
    const float* __restrict__ decay,
    float* __restrict__ Sstart, float* __restrict__ Zstart) {
  const int idx = blockIdx.x * 256 + threadIdx.x;  // 0..2047
  const int c = idx & 255;
  const int b = idx >> 8;
  const float w = decay[c] * (1.0f / TDIM);
  const float ewL = __expf(w * (float)CHLEN);
  float S = 0.0f, Z = 0.0f;
  for (int j = 0; j < NCHUNK; j++) {
    long long o = ((long long)b * NCHUNK + j) * CDIM + c;
    Sstart[o] = S;
    Zstart[o] = Z;
    S = ewL * S + Sloc[o];
    Z = ewL * Z + Zloc[o];
  }
}

__global__ __launch_bounds__(256) void wkv_phase3(
    const __bf16* __restrict__ kvr, const float* __restrict__ decay,
    const float* __restrict__ first, const float* __restrict__ Sstart,
    const float* __restrict__ Zstart, __bf16* __restrict__ a2) {
  const int c = threadIdx.x;
  const int chunk = blockIdx.x & (NCHUNK - 1);
  const int b = blockIdx.x >> 6;
  const float w = decay[c] * (1.0f / TDIM);
  const float u = first[c] * (1.0f / TDIM);
  const float ew = __expf(w);
  const float eu = __expf(u);
  long long so = ((long long)b * NCHUNK + chunk) * CDIM + c;
  float S = Sstart[so], Z = Zstart[so];
  long long base = ((long long)b * TDIM + (long long)chunk * CHLEN) * 768 + c;
  long long obase = ((long long)b * TDIM + (long long)chunk * CHLEN) * CDIM + c;
  for (int t = 0; t < CHLEN; t++) {
    float kt = (float)kvr[base + (long long)t * 768];
    float vt = (float)kvr[base + (long long)t * 768 + 256];
    float rt = (float)kvr[base + (long long)t * 768 + 512];
    float ek = __expf(kt);
    float E = eu * ek;
    float y = (S + E * vt) / (Z + E);
    float sr = 1.0f / (1.0f + __expf(-rt));
    a2[obase + (long long)t * CDIM] = (__bf16)(sr * y);
    S = ew * S + ek * vt;
    Z = ew * Z + ek;
  }
}

// ---------------------------------------------------------------------------
// Workspace layout (peak ~170.5 MB, same as round 1):
//   [0)       h (bf16, 16 MB)     -> reused as a2, then g2buf
//   [16 MB)   kvr (bf16, 48 MB)   -> first 16 MB reused as h2
//   [64 MB)   x1 (f32, 32 MB)
//   [96 MB)   scan state (2 MB, dead before EPI2) then kk (bf16, 64 MB)
//   [160 MB)  packed bf16 weights (~1.7 MB)
// ---------------------------------------------------------------------------
extern "C" void kernel_launch(void* const* d_in, const int* in_sizes, int n_in,
                              void* d_out, int out_size, void* d_ws, size_t ws_size,
                              hipStream_t stream) {
  const float* x     = (const float*)d_in[0];
  const float* Wk    = (const float*)d_in[1];
  const float* Wv    = (const float*)d_in[2];
  const float* Wr    = (const float*)d_in[3];
  const float* Wo    = (const float*)d_in[4];
  const float* Wkf   = (const float*)d_in[5];
  const float* Wvf   = (const float*)d_in[6];
  const float* Wrf   = (const float*)d_in[7];
  const float* g1    = (const float*)d_in[8];
  const float* b1    = (const float*)d_in[9];
  const float* g2    = (const float*)d_in[10];
  const float* b2    = (const float*)d_in[11];
  const float* decay = (const float*)d_in[12];
  const float* first = (const float*)d_in[13];
  float* out = (float*)d_out;
  char* ws = (char*)d_ws;

  __bf16* hbuf   = (__bf16*)(ws + 0);               // h -> a2 -> g2buf
  __bf16* kvr    = (__bf16*)(ws + 16777216LL);
  __bf16* h2     = (__bf16*)(ws + 16777216LL);      // aliases kvr (dead by then)
  float*  x1     = (float*)(ws + 67108864LL);
  float*  Sloc   = (float*)(ws + 100663296LL);      // scan state: dead before kk
  float*  Zloc   = (float*)(ws + 101187584LL);
  float*  Sstart = (float*)(ws + 101711872LL);
  float*  Zstart = (float*)(ws + 102236160LL);
  __bf16* kk     = (__bf16*)(ws + 100663296LL);     // overwrites scan state (safe)
  __bf16* WkvrT  = (__bf16*)(ws + 167772160LL);
  __bf16* WoT    = (__bf16*)(ws + 168165376LL);
  __bf16* WkfT   = (__bf16*)(ws + 168296448LL);
  __bf16* WvfT   = (__bf16*)(ws + 168820736LL);
  __bf16* WrfT   = (__bf16*)(ws + 169345024LL);

  pack_weights<<<3328, 256, 0, stream>>>(Wk, Wv, Wr, Wo, Wkf, Wvf, Wrf,
                                         WkvrT, WoT, WkfT, WvfT, WrfT);

  // --- SpatialMix ---
  ln_kernel<<<NTOK, 256, 0, stream>>>(x, g1, b1, hbuf);
  gemm_kernel<0><<<dim3(NTOK / BM, 768 / BN), 256, 0, stream>>>(
      hbuf, WkvrT, NTOK, 768, CDIM, nullptr, kvr, nullptr, nullptr);
  wkv_phase1<<<BDIM * NCHUNK, 256, 0, stream>>>(kvr, decay, Sloc, Zloc);
  wkv_phase2<<<BDIM, 256, 0, stream>>>(Sloc, Zloc, decay, Sstart, Zstart);
  wkv_phase3<<<BDIM * NCHUNK, 256, 0, stream>>>(kvr, decay, first, Sstart, Zstart, hbuf);
  gemm_kernel<1><<<dim3(NTOK / BM, CDIM / BN), 256, 0, stream>>>(
      hbuf, WoT, NTOK, CDIM, CDIM, x1, nullptr, x, nullptr);

  // --- ChannelMix ---
  ln_kernel<<<NTOK, 256, 0, stream>>>(x1, g2, b2, h2);
  gemm_kernel<2><<<dim3(NTOK / BM, HIDDIM / BN), 256, 0, stream>>>(
      h2, WkfT, NTOK, HIDDIM, CDIM, nullptr, kk, nullptr, nullptr);
  gemm_kernel<3><<<dim3(NTOK / BM, CDIM / BN), 256, 0, stream>>>(
      h2, WrfT, NTOK, CDIM, CDIM, nullptr, hbuf, nullptr, nullptr);   // g2buf = hbuf
  gemm_kernel<4><<<dim3(NTOK / BM, CDIM / BN), 256, 0, stream>>>(
      kk, WvfT, NTOK, CDIM, HIDDIM, out, nullptr, x1, hbuf);
}

// Round 3
// 312.797 us; speedup vs baseline: 1.0399x; 1.0399x over previous
//
#include <hip/hip_runtime.h>
#include <hip/hip_bf16.h>
#include <math.h>

// Problem constants
#define TDIM 4096
#define CDIM 256
#define BDIM 8
#define NTOK (BDIM * TDIM)   // 32768 rows
#define HIDDIM 1024
#define NCHUNK 64
#define CHLEN 64             // 4096 / 64

typedef float f32x4 __attribute__((ext_vector_type(4)));
typedef __bf16 bf16x8 __attribute__((ext_vector_type(8)));
typedef __bf16 bf16x4 __attribute__((ext_vector_type(4)));

// async global->LDS, 16 B/lane, lands at wave-uniform base + lane*16
#define GLDS16(gp, lp) __builtin_amdgcn_global_load_lds( \
    (const __attribute__((address_space(1))) void*)(gp), \
    (__attribute__((address_space(3))) void*)(lp), 16, 0, 0)

// s_waitcnt imm (gfx9 encoding): vmcnt[3:0]|expcnt[6:4]|lgkmcnt[11:8]|vmcnt_hi[15:14]
#define WAITCNT_VM4 0x0F74   // vmcnt<=4, lgkm/exp unconstrained
#define WAITCNT_VM0 0x0F70   // vmcnt==0, lgkm/exp unconstrained

// ---------------------------------------------------------------------------
// Weight pack: fp32 [K,N] -> bf16 transposed [N,K].
// ---------------------------------------------------------------------------
__global__ __launch_bounds__(256) void pack_weights(
    const float* __restrict__ Wk, const float* __restrict__ Wv,
    const float* __restrict__ Wr, const float* __restrict__ Wo,
    const float* __restrict__ Wkf, const float* __restrict__ Wvf,
    const float* __restrict__ Wrf,
    __bf16* __restrict__ WkvrT, __bf16* __restrict__ WoT,
    __bf16* __restrict__ WkfT, __bf16* __restrict__ WvfT,
    __bf16* __restrict__ WrfT) {
  long long j = (long long)blockIdx.x * 256 + threadIdx.x;
  if (j < 196608) {  // WkvrT: [768][256]
    int n = (int)(j >> 8), k = (int)(j & 255);
    const float* src = (n < 256) ? Wk : (n < 512 ? Wv : Wr);
    WkvrT[j] = (__bf16)src[k * 256 + (n & 255)];
    return;
  }
  j -= 196608;
  if (j < 65536) { int n = (int)(j >> 8), k = (int)(j & 255);
    WoT[j] = (__bf16)Wo[k * 256 + n]; return; }
  j -= 65536;
  if (j < 262144) { int n = (int)(j >> 8), k = (int)(j & 255);   // WkfT [1024][256]
    WkfT[j] = (__bf16)Wkf[(long long)k * 1024 + n]; return; }
  j -= 262144;
  if (j < 262144) { int n = (int)(j >> 10), k = (int)(j & 1023); // WvfT [256][1024]
    WvfT[j] = (__bf16)Wvf[(long long)k * 256 + n]; return; }
  j -= 262144;
  if (j < 65536) { int n = (int)(j >> 8), k = (int)(j & 255);
    WrfT[j] = (__bf16)Wrf[k * 256 + n]; return; }
}

// ---------------------------------------------------------------------------
// LayerNorm over C=256, one block per row, bf16 output.
// ---------------------------------------------------------------------------
__global__ __launch_bounds__(256) void ln_kernel(
    const float* __restrict__ x, const float* __restrict__ gamma,
    const float* __restrict__ beta, __bf16* __restrict__ h) {
  __shared__ float red[8];
  const long long row = blockIdx.x;
  const int tid = threadIdx.x;
  float v = x[row * CDIM + tid];
  float s = v, s2 = v * v;
  #pragma unroll
  for (int o = 1; o < 64; o <<= 1) { s += __shfl_xor(s, o); s2 += __shfl_xor(s2, o); }
  const int wave = tid >> 6, lane = tid & 63;
  if (lane == 0) { red[wave] = s; red[4 + wave] = s2; }
  __syncthreads();
  s = red[0] + red[1] + red[2] + red[3];
  s2 = red[4] + red[5] + red[6] + red[7];
  const float mean = s * (1.0f / CDIM);
  const float var = s2 * (1.0f / CDIM) - mean * mean;
  const float rstd = rsqrtf(var + 1e-5f);
  h[row * CDIM + tid] = (__bf16)((v - mean) * rstd * gamma[tid] + beta[tid]);
}

// ---------------------------------------------------------------------------
// bf16 MFMA GEMM, 3-stage software-pipelined K-loop.
//   C[M,N] = A[M,K] * Bt[N,K]^T   (Bt pre-transposed [N,K])
// 128x128 tile, 4 waves x (64x64). Triple-buffered LDS; loads for iter i+2
// issued right after iter i's barrier; raw s_barrier + partial vmcnt wait
// keeps the prefetch in flight across the barrier (prefetch distance 2).
// Accumulator computed TRANSPOSED (mfma(fb,fa)): lane holds 4 consecutive
// COLUMNS -> float4/short4 epilogue.
// Epilogues: 0 bf16=acc | 1 f32=src+acc | 2 bf16=relu(acc)^2
//            3 bf16=sigmoid(acc) | 4 f32=src+gate*acc
// ---------------------------------------------------------------------------
#define BM 128
#define BN 128
#define BK 32

template <int EPI>
__global__ __launch_bounds__(256) void gemm_kernel(
    const __bf16* __restrict__ A, const __bf16* __restrict__ Bt,
    int M, int N, int K,
    float* __restrict__ outF, __bf16* __restrict__ outH,
    const float* __restrict__ src, const __bf16* __restrict__ gate) {
  __shared__ __bf16 sA[3][BM * BK];   // unpadded row-major [row][k], 64 B/row
  __shared__ __bf16 sB[3][BN * BK];
  const int tid = threadIdx.x;
  const int wave = tid >> 6, lane = tid & 63;
  const int quad = lane >> 4, mrow = lane & 15;
  const long long bm = (long long)blockIdx.x * BM;
  const long long bn = (long long)blockIdx.y * BN;
  const int wm = (wave & 1) * 64, wn = (wave >> 1) * 64;

  // staging: wave w covers rows [w*32, w*32+32) of both tiles, 2 calls each
  const int lrow = lane >> 2;          // 0..15
  const int lk = (lane & 3) * 8;       // elem offset 0,8,16,24
  const int ar0 = wave * 32;

  const __bf16* gA = A + (bm + ar0 + lrow) * (long long)K + lk;
  const __bf16* gB = Bt + (bn + ar0 + lrow) * (long long)K + lk;

  auto issue = [&](int g) {
    const int buf = g % 3;
    const long long k0 = (long long)g * BK;
    GLDS16(gA + k0, &sA[buf][ar0 * BK]);
    GLDS16(gA + k0 + 16LL * K, &sA[buf][(ar0 + 16) * BK]);
    GLDS16(gB + k0, &sB[buf][ar0 * BK]);
    GLDS16(gB + k0 + 16LL * K, &sB[buf][(ar0 + 16) * BK]);
  };

  f32x4 acc[4][4] = {};   // acc[rt][nt], TRANSPOSED

  const int nit = K / BK;
  issue(0);
  issue(1);

  auto compute = [&](int i) {
    const int buf = i % 3;
    bf16x8 fa[4], fb[4];
    #pragma unroll
    for (int rt = 0; rt < 4; rt++)
      fa[rt] = *(const bf16x8*)&sA[buf][(wm + rt * 16 + mrow) * BK + quad * 8];
    #pragma unroll
    for (int nt = 0; nt < 4; nt++)
      fb[nt] = *(const bf16x8*)&sB[buf][(wn + nt * 16 + mrow) * BK + quad * 8];
    #pragma unroll
    for (int rt = 0; rt < 4; rt++)
      #pragma unroll
      for (int nt = 0; nt < 4; nt++)
        acc[rt][nt] = __builtin_amdgcn_mfma_f32_16x16x32_bf16(fb[nt], fa[rt], acc[rt][nt], 0, 0, 0);
  };

  #pragma unroll 1
  for (int i = 0; i < nit - 1; i++) {
    __builtin_amdgcn_s_waitcnt(WAITCNT_VM4);   // group i landed; i+1 in flight
    __builtin_amdgcn_s_barrier();              // all waves done reading buf (i+2)%3
    if (i + 2 < nit) issue(i + 2);             // prefetch distance 2
    compute(i);
  }
  __builtin_amdgcn_s_waitcnt(WAITCNT_VM0);
  __builtin_amdgcn_s_barrier();
  compute(nit - 1);

  // Transposed C/D layout: lane (quad,mrow) reg r -> row = m-tile + mrow,
  // col = n-tile + quad*4 + r. 4 consecutive cols per lane.
  #pragma unroll
  for (int rt = 0; rt < 4; rt++) {
    #pragma unroll
    for (int nt = 0; nt < 4; nt++) {
      const long long row = bm + wm + rt * 16 + mrow;
      const long long colb = bn + wn + nt * 16 + quad * 4;
      const long long idx = row * N + colb;
      const f32x4 a = acc[rt][nt];
      if (EPI == 0) {
        bf16x4 o; o[0] = (__bf16)a[0]; o[1] = (__bf16)a[1];
        o[2] = (__bf16)a[2]; o[3] = (__bf16)a[3];
        *(bf16x4*)&outH[idx] = o;
      } else if (EPI == 1) {
        *(f32x4*)&outF[idx] = *(const f32x4*)&src[idx] + a;
      } else if (EPI == 2) {
        bf16x4 o;
        #pragma unroll
        for (int r = 0; r < 4; r++) { float t = a[r] > 0.0f ? a[r] : 0.0f; o[r] = (__bf16)(t * t); }
        *(bf16x4*)&outH[idx] = o;
      } else if (EPI == 3) {
        bf16x4 o;
        #pragma unroll
        for (int r = 0; r < 4; r++) o[r] = (__bf16)(1.0f / (1.0f + __expf(-a[r])));
        *(bf16x4*)&outH[idx] = o;
      } else {
        const f32x4 s4 = *(const f32x4*)&src[idx];
        const bf16x4 g4 = *(const bf16x4*)&gate[idx];
        f32x4 o;
        #pragma unroll
        for (int r = 0; r < 4; r++) o[r] = s4[r] + (float)g4[r] * a[r];
        *(f32x4*)&outF[idx] = o;
      }
    }
  }
}

// ---------------------------------------------------------------------------
// WKV chunked scan (direct fp32 recurrence; exponents bounded: |w*T|<=5,
// |k|~O(2), u~0).  S' = e^w S + e^k v ; y = (S + e^{u+k} v)/(Z + e^{u+k})
// ---------------------------------------------------------------------------
__global__ __launch_bounds__(256) void wkv_phase1(
    const __bf16* __restrict__ kvr, const float* __restrict__ decay,
    float* __restrict__ Sloc, float* __restrict__ Zloc) {
  const int c = threadIdx.x;
  const int chunk = blockIdx.x & (NCHUNK - 1);
  const int b = blockIdx.x >> 6;
  const float w = decay[c] * (1.0f / TDIM);
  const float ew = __expf(w);
  float S = 0.0f, Z = 0.0f;
  long long base = ((long long)b * TDIM + (long long)chunk * CHLEN) * 768 + c;
  for (int t = 0; t < CHLEN; t++) {
    float kt = (float)kvr[base + (long long)t * 768];
    float vt = (float)kvr[base + (long long)t * 768 + 256];
    float ek = __expf(kt);
    S = ew * S + ek * vt;
    Z = ew * Z + ek;
  }
  long long o = ((long long)b * NCHUNK + chunk) * CDIM + c;
  Sloc[o] = S;
  Zloc[o] = Z;
}

__global__ __launch_bounds__(256) void wkv_phase2(
    const float* __restrict__ Sloc, const float* __restrict__ Zloc,
    const float* __restrict__ decay,
    float* __restrict__ Sstart, float* __restrict__ Zstart) {
  const int idx = blockIdx.x * 256 + threadIdx.x;  // 0..2047
  const int c = idx & 255;
  const int b = idx >> 8;
  const float w = decay[c] * (1.0f / TDIM);
  const float ewL = __expf(w * (float)CHLEN);
  float S = 0.0f, Z = 0.0f;
  for (int j = 0; j < NCHUNK; j++) {
    long long o = ((long long)b * NCHUNK + j) * CDIM + c;
    Sstart[o] = S;
    Zstart[o] = Z;
    S = ewL * S + Sloc[o];
    Z = ewL * Z + Zloc[o];
  }
}

__global__ __launch_bounds__(256) void wkv_phase3(
    const __bf16* __restrict__ kvr, const float* __restrict__ decay,
    const float* __restrict__ first, const float* __restrict__ Sstart,
    const float* __restrict__ Zstart, __bf16* __restrict__ a2) {
  const int c = threadIdx.x;
  const int chunk = blockIdx.x & (NCHUNK - 1);
  const int b = blockIdx.x >> 6;
  const float w = decay[c] * (1.0f / TDIM);
  const float u = first[c] * (1.0f / TDIM);
  const float ew = __expf(w);
  const float eu = __expf(u);
  long long so = ((long long)b * NCHUNK + chunk) * CDIM + c;
  float S = Sstart[so], Z = Zstart[so];
  long long base = ((long long)b * TDIM + (long long)chunk * CHLEN) * 768 + c;
  long long obase = ((long long)b * TDIM + (long long)chunk * CHLEN) * CDIM + c;
  for (int t = 0; t < CHLEN; t++) {
    float kt = (float)kvr[base + (long long)t * 768];
    float vt = (float)kvr[base + (long long)t * 768 + 256];
    float rt = (float)kvr[base + (long long)t * 768 + 512];
    float ek = __expf(kt);
    float E = eu * ek;
    float y = (S + E * vt) / (Z + E);
    float sr = 1.0f / (1.0f + __expf(-rt));
    a2[obase + (long long)t * CDIM] = (__bf16)(sr * y);
    S = ew * S + ek * vt;
    Z = ew * Z + ek;
  }
}

// ---------------------------------------------------------------------------
// Workspace layout (peak ~170.5 MB):
//   [0)       h (bf16, 16 MB)     -> reused as a2, then g2buf
//   [16 MB)   kvr (bf16, 48 MB)   -> first 16 MB reused as h2
//   [64 MB)   x1 (f32, 32 MB)
//   [96 MB)   scan state (2 MB, dead before EPI2) then kk (bf16, 64 MB)
//   [160 MB)  packed bf16 weights (~1.7 MB)
// ---------------------------------------------------------------------------
extern "C" void kernel_launch(void* const* d_in, const int* in_sizes, int n_in,
                              void* d_out, int out_size, void* d_ws, size_t ws_size,
                              hipStream_t stream) {
  const float* x     = (const float*)d_in[0];
  const float* Wk    = (const float*)d_in[1];
  const float* Wv    = (const float*)d_in[2];
  const float* Wr    = (const float*)d_in[3];
  const float* Wo    = (const float*)d_in[4];
  const float* Wkf   = (const float*)d_in[5];
  const float* Wvf   = (const float*)d_in[6];
  const float* Wrf   = (const float*)d_in[7];
  const float* g1    = (const float*)d_in[8];
  const float* b1    = (const float*)d_in[9];
  const float* g2    = (const float*)d_in[10];
  const float* b2    = (const float*)d_in[11];
  const float* decay = (const float*)d_in[12];
  const float* first = (const float*)d_in[13];
  float* out = (float*)d_out;
  char* ws = (char*)d_ws;

  __bf16* hbuf   = (__bf16*)(ws + 0);               // h -> a2 -> g2buf
  __bf16* kvr    = (__bf16*)(ws + 16777216LL);
  __bf16* h2     = (__bf16*)(ws + 16777216LL);      // aliases kvr (dead by then)
  float*  x1     = (float*)(ws + 67108864LL);
  float*  Sloc   = (float*)(ws + 100663296LL);      // scan state: dead before kk
  float*  Zloc   = (float*)(ws + 101187584LL);
  float*  Sstart = (float*)(ws + 101711872LL);
  float*  Zstart = (float*)(ws + 102236160LL);
  __bf16* kk     = (__bf16*)(ws + 100663296LL);     // overwrites scan state (safe)
  __bf16* WkvrT  = (__bf16*)(ws + 167772160LL);
  __bf16* WoT    = (__bf16*)(ws + 168165376LL);
  __bf16* WkfT   = (__bf16*)(ws + 168296448LL);
  __bf16* WvfT   = (__bf16*)(ws + 168820736LL);
  __bf16* WrfT   = (__bf16*)(ws + 169345024LL);

  pack_weights<<<3328, 256, 0, stream>>>(Wk, Wv, Wr, Wo, Wkf, Wvf, Wrf,
                                         WkvrT, WoT, WkfT, WvfT, WrfT);

  // --- SpatialMix ---
  ln_kernel<<<NTOK, 256, 0, stream>>>(x, g1, b1, hbuf);
  gemm_kernel<0><<<dim3(NTOK / BM, 768 / BN), 256, 0, stream>>>(
      hbuf, WkvrT, NTOK, 768, CDIM, nullptr, kvr, nullptr, nullptr);
  wkv_phase1<<<BDIM * NCHUNK, 256, 0, stream>>>(kvr, decay, Sloc, Zloc);
  wkv_phase2<<<BDIM, 256, 0, stream>>>(Sloc, Zloc, decay, Sstart, Zstart);
  wkv_phase3<<<BDIM * NCHUNK, 256, 0, stream>>>(kvr, decay, first, Sstart, Zstart, hbuf);
  gemm_kernel<1><<<dim3(NTOK / BM, CDIM / BN), 256, 0, stream>>>(
      hbuf, WoT, NTOK, CDIM, CDIM, x1, nullptr, x, nullptr);

  // --- ChannelMix ---
  ln_kernel<<<NTOK, 256, 0, stream>>>(x1, g2, b2, h2);
  gemm_kernel<2><<<dim3(NTOK / BM, HIDDIM / BN), 256, 0, stream>>>(
      h2, WkfT, NTOK, HIDDIM, CDIM, nullptr, kk, nullptr, nullptr);
  gemm_kernel<3><<<dim3(NTOK / BM, CDIM / BN), 256, 0, stream>>>(
      h2, WrfT, NTOK, CDIM, CDIM, nullptr, hbuf, nullptr, nullptr);   // g2buf = hbuf
  gemm_kernel<4><<<dim3(NTOK / BM, CDIM / BN), 256, 0, stream>>>(
      kk, WvfT, NTOK, CDIM, HIDDIM, out, nullptr, x1, hbuf);
}